// Round 1
// baseline (742.519 us; speedup 1.0000x reference)
//
#include <hip/hip_runtime.h>
#include <math.h>

// NLL of a Gaussian mixed model via double Schur complement / Woodbury.
// N=4096 points, two random-effect factors with Q0=1000, Q1=500 groups.
// Reduces the N x N solve to a 500x500 (padded 512) Cholesky.

constexpr int N_PTS = 4096;
constexpr int Q0 = 1000;
constexpr int Q1 = 500;
constexpr int QP = 512;            // Schur dim padded with identity to 512
constexpr float LOG_2PI = 1.8378770664093453f;

// ---- workspace layout (float offsets) ----
constexpr int OFF_CNT = 0;              // cross counts CNT[Q0][Q1]
constexpr int OFF_C0  = 500000;         // counts factor 0 [Q0]
constexpr int OFF_C1  = 501000;         // counts factor 1 [Q1]
constexpr int OFF_U0  = 501504;         // sum of r per group, factor 0 [Q0]
constexpr int OFF_U1  = 502504;         // sum of r per group, factor 1 [Q1]
constexpr int OFF_SC  = 503008;         // scalars: [0] = r^T r
constexpr int OFF_S   = 503040;         // Schur matrix S [QP][QP], row stride QP
constexpr int ZERO_FLOATS = 503040;     // everything before S needs zeroing

// ------------------------------------------------------------------
// 1) scatter: counts, cross counts, group sums of residual, r^T r
// ------------------------------------------------------------------
__global__ __launch_bounds__(256) void k_scatter(const float* __restrict__ yt,
                                                 const float* __restrict__ yp,
                                                 const int* __restrict__ z0,
                                                 const int* __restrict__ z1,
                                                 float* __restrict__ ws) {
    int i = blockIdx.x * blockDim.x + threadIdx.x;
    float r = 0.f;
    if (i < N_PTS) {
        r = yt[i] - yp[i];
        int i0 = z0[i];
        int i1 = z1[i];
        atomicAdd(&ws[OFF_C0 + i0], 1.0f);
        atomicAdd(&ws[OFF_C1 + i1], 1.0f);
        atomicAdd(&ws[OFF_CNT + i0 * Q1 + i1], 1.0f);
        atomicAdd(&ws[OFF_U0 + i0], r);
        atomicAdd(&ws[OFF_U1 + i1], r);
    }
    float r2 = r * r;
    #pragma unroll
    for (int off = 32; off; off >>= 1) r2 += __shfl_down(r2, off, 64);
    if ((threadIdx.x & 63) == 0) atomicAdd(&ws[OFF_SC + 0], r2);
}

// ------------------------------------------------------------------
// 2) build S = D1 - B^T A^{-1} B  (padded to QP with identity)
//    S[i][j] = delta_ij*(1/sb1 + C1[i]/se)
//              - (1/se^2) * sum_g0 CNT[g0][i]*CNT[g0][j] / a[g0]
//    a[g0] = 1/sb0 + C0[g0]/se
// ------------------------------------------------------------------
__global__ __launch_bounds__(256) void k_build_s(const float* __restrict__ sig2e,
                                                 const float* __restrict__ sig2bs,
                                                 float* __restrict__ ws) {
    const float se = sig2e[0], sb0 = sig2bs[0], sb1 = sig2bs[1];
    const float inv_se = 1.f / se, inv_sb0 = 1.f / sb0, inv_sb1 = 1.f / sb1;
    const float* CNT = ws + OFF_CNT;
    const float* C0w = ws + OFF_C0;
    const float* C1w = ws + OFF_C1;
    float* S = ws + OFF_S;

    __shared__ float tI[32][17];
    __shared__ float tJ[32][17];
    __shared__ float wv[32];

    int tx = threadIdx.x, ty = threadIdx.y;
    int t = ty * 16 + tx;
    int i = blockIdx.y * 16 + ty;     // row of S
    int j = blockIdx.x * 16 + tx;     // col of S

    float acc = 0.f;
    for (int g0c = 0; g0c < Q0; g0c += 32) {
        #pragma unroll
        for (int l = 0; l < 2; ++l) {
            int e = t + l * 256;
            int kk = e >> 4, col = e & 15;
            int g0 = g0c + kk;
            int gi = blockIdx.y * 16 + col;
            int gj = blockIdx.x * 16 + col;
            tI[kk][col] = (g0 < Q0 && gi < Q1) ? CNT[g0 * Q1 + gi] : 0.f;
            tJ[kk][col] = (g0 < Q0 && gj < Q1) ? CNT[g0 * Q1 + gj] : 0.f;
        }
        if (t < 32) {
            int g0 = g0c + t;
            wv[t] = (g0 < Q0) ? 1.f / (inv_sb0 + C0w[g0] * inv_se) : 0.f;
        }
        __syncthreads();
        #pragma unroll
        for (int kk = 0; kk < 32; ++kk) acc += wv[kk] * (tI[kk][ty] * tJ[kk][tx]);
        __syncthreads();
    }

    float val;
    if (i < Q1 && j < Q1) {
        val = -inv_se * inv_se * acc;
        if (i == j) val += inv_sb1 + C1w[i] * inv_se;
    } else {
        val = (i == j) ? 1.f : 0.f;   // identity padding
    }
    S[i * QP + j] = val;
}

// ------------------------------------------------------------------
// 3a) panel kernel (single WG): factor 64x64 diagonal block (LDS),
//     then triangular-solve the panel below it (thread-per-row).
//     Only the lower triangle of S is maintained.
// ------------------------------------------------------------------
__global__ __launch_bounds__(512) void k_panel(float* __restrict__ ws, int x) {
    float* S = ws + OFF_S;
    __shared__ float D[64][65];
    int tid = threadIdx.x;

    #pragma unroll
    for (int it = 0; it < 8; ++it) {
        int e = tid + it * 512;
        int ii = e >> 6, kk = e & 63;
        D[ii][kk] = S[(x + ii) * QP + x + kk];
    }
    __syncthreads();

    // right-looking Cholesky of D in LDS
    for (int j = 0; j < 64; ++j) {
        if (tid < 64) {   // wave 0 only: read-before-write safe within one wave
            float sd = sqrtf(D[j][j]);
            if (tid == j) D[j][j] = sd;
            else if (tid > j) D[tid][j] = D[tid][j] / sd;
        }
        __syncthreads();
        #pragma unroll
        for (int it = 0; it < 8; ++it) {
            int e = tid + it * 512;
            int ii = e >> 6, kk = e & 63;
            if (kk > j && ii >= kk) D[ii][kk] -= D[ii][j] * D[kk][j];
        }
        __syncthreads();
    }

    // write factored block back
    #pragma unroll
    for (int it = 0; it < 8; ++it) {
        int e = tid + it * 512;
        int ii = e >> 6, kk = e & 63;
        S[(x + ii) * QP + x + kk] = D[ii][kk];
    }

    // panel triangular solve: P <- P * L_D^{-T}, one thread per row
    int r = x + 64 + tid;
    if (r < QP) {
        float p[64];
        const float* row = S + r * QP + x;
        #pragma unroll
        for (int j = 0; j < 64; ++j) p[j] = row[j];
        #pragma unroll
        for (int j = 0; j < 64; ++j) {
            float pj = p[j] / D[j][j];
            p[j] = pj;
            #pragma unroll
            for (int k = j + 1; k < 64; ++k) p[k] -= pj * D[k][j];
        }
        float* wrow = S + r * QP + x;
        #pragma unroll
        for (int j = 0; j < 64; ++j) wrow[j] = p[j];
    }
}

// ------------------------------------------------------------------
// 3b) trailing SYRK update: S[i][k] -= sum_j P[i][j]*P[k][j] (lower only)
//     grid (T,T), keep tiles with ti >= tj
// ------------------------------------------------------------------
__global__ __launch_bounds__(256) void k_update(float* __restrict__ ws, int x) {
    float* S = ws + OFF_S;
    int ti = blockIdx.y, tj = blockIdx.x;
    if (tj > ti) return;
    int ri = x + 64 + ti * 64;
    int rj = x + 64 + tj * 64;

    __shared__ float Pi[64][65];
    __shared__ float Pj[64][65];
    int tid = threadIdx.x;

    #pragma unroll
    for (int it = 0; it < 16; ++it) {
        int e = tid + it * 256;
        int a = e >> 6, b = e & 63;
        Pi[a][b] = S[(ri + a) * QP + x + b];
        Pj[a][b] = S[(rj + a) * QP + x + b];
    }
    __syncthreads();

    int ta = tid >> 4, tb = tid & 15;   // 16x16 threads, 4x4 micro-tile
    float acc[4][4] = {{0.f}};
    #pragma unroll
    for (int j = 0; j < 64; ++j) {
        float pa[4], pb[4];
        #pragma unroll
        for (int u = 0; u < 4; ++u) { pa[u] = Pi[ta * 4 + u][j]; pb[u] = Pj[tb * 4 + u][j]; }
        #pragma unroll
        for (int u = 0; u < 4; ++u)
            #pragma unroll
            for (int v = 0; v < 4; ++v) acc[u][v] += pa[u] * pb[v];
    }

    if (ti > tj) {
        #pragma unroll
        for (int u = 0; u < 4; ++u) {
            float4* ptr = (float4*)&S[(ri + ta * 4 + u) * QP + rj + tb * 4];
            float4 cv = *ptr;
            cv.x -= acc[u][0]; cv.y -= acc[u][1]; cv.z -= acc[u][2]; cv.w -= acc[u][3];
            *ptr = cv;
        }
    } else {
        #pragma unroll
        for (int u = 0; u < 4; ++u)
            #pragma unroll
            for (int v = 0; v < 4; ++v) {
                int gi = ri + ta * 4 + u, gj = rj + tb * 4 + v;
                if (gi >= gj) S[gi * QP + gj] -= acc[u][v];
            }
    }
}

// ------------------------------------------------------------------
// 4) final: rhs v = u1 - B^T A^{-1} u0, forward solve L z = v,
//    reductions and scalar combine.
// ------------------------------------------------------------------
__global__ __launch_bounds__(512) void k_final(const float* __restrict__ sig2e,
                                               const float* __restrict__ sig2bs,
                                               float* __restrict__ ws,
                                               float* __restrict__ out) {
    const float se = sig2e[0], sb0 = sig2bs[0], sb1 = sig2bs[1];
    const float inv_se = 1.f / se, inv_sb0 = 1.f / sb0, inv_sb1 = 1.f / sb1;
    const float* CNT = ws + OFF_CNT;
    const float* C0w = ws + OFF_C0;
    const float* U0 = ws + OFF_U0;
    const float* U1 = ws + OFF_U1;
    float* S = ws + OFF_S;

    __shared__ float wu0[Q0];
    __shared__ float vs[QP];
    __shared__ float Dl[64][65];
    __shared__ float red[512];
    int tid = threadIdx.x;

    // phase 1: per-group-0 weights, logdet(A) partial, u0^T A^{-1} u0 partial
    float la = 0.f, q0p = 0.f;
    for (int g0 = tid; g0 < Q0; g0 += 512) {
        float a = inv_sb0 + C0w[g0] * inv_se;
        float w = 1.f / a;
        float wu = w * U0[g0];
        wu0[g0] = wu;
        la += logf(a);
        q0p += U0[g0] * wu;
    }
    __syncthreads();

    // phase 2: v = u1 - (1/se) * CNT^T (w .* u0)   (coalesced column per thread)
    float vacc = 0.f;
    if (tid < Q1) {
        #pragma unroll 4
        for (int g0 = 0; g0 < Q0; ++g0) vacc += CNT[g0 * Q1 + tid] * wu0[g0];
    }
    vs[tid] = (tid < Q1) ? (U1[tid] - inv_se * vacc) : 0.f;
    __syncthreads();

    // phase 3: blocked forward substitution L z = v (z overwrites vs)
    for (int c = 0; c < 8; ++c) {
        int base = c * 64;
        #pragma unroll
        for (int it = 0; it < 8; ++it) {
            int e = tid + it * 512;
            int ii = e >> 6, kk = e & 63;
            Dl[ii][kk] = S[(base + ii) * QP + base + kk];
        }
        __syncthreads();
        if (tid < 64) {   // wave 0: shfl-based in-register solve of 64 unknowns
            float z = vs[base + tid];
            for (int j = 0; j < 64; ++j) {
                float zj = __shfl(z, j, 64) / Dl[j][j];
                if (tid == j) z = zj;
                else if (tid > j) z -= Dl[tid][j] * zj;
            }
            vs[base + tid] = z;
        }
        __syncthreads();
        int r = base + 64 + tid;
        if (r < QP) {
            float acc = 0.f;
            const float* row = S + r * QP + base;
            #pragma unroll
            for (int j = 0; j < 64; ++j) acc += row[j] * vs[base + j];
            vs[r] -= acc;
        }
        __syncthreads();
    }

    // per-thread partials: quad form of z, logdet(S)
    float z = vs[tid];
    float q1p = z * z;
    float ldp = logf(S[tid * QP + tid]);   // padded diag == 1 -> contributes 0

    // block reductions (4 values)
    float sums[4];
    float vals[4] = {la, q0p, q1p, ldp};
    for (int m = 0; m < 4; ++m) {
        __syncthreads();
        red[tid] = vals[m];
        __syncthreads();
        if (tid < 256) red[tid] += red[tid + 256];
        __syncthreads();
        if (tid < 128) red[tid] += red[tid + 128];
        __syncthreads();
        if (tid < 64) red[tid] += red[tid + 64];
        __syncthreads();
        float xv = 0.f;
        if (tid < 64) {
            xv = red[tid];
            #pragma unroll
            for (int o = 32; o; o >>= 1) xv += __shfl_down(xv, o, 64);
        }
        sums[m] = xv;
    }

    if (tid == 0) {
        float rtr = ws[OFF_SC + 0];
        float umu = sums[1] + sums[2];                       // u^T M^{-1} u
        float loss2 = inv_se * rtr - inv_se * inv_se * umu;  // r^T V^{-1} r
        float logdetV = (float)N_PTS * logf(se)
                      + (float)Q0 * logf(sb0)
                      + (float)Q1 * logf(sb1)
                      + sums[0]                              // sum log a[g0]
                      + 2.f * sums[3];                       // logdet of S via L
        out[0] = 0.5f * ((float)N_PTS * LOG_2PI + logdetV + loss2);
    }
}

// ------------------------------------------------------------------
extern "C" void kernel_launch(void* const* d_in, const int* in_sizes, int n_in,
                              void* d_out, int out_size, void* d_ws, size_t ws_size,
                              hipStream_t stream) {
    const float* yt = (const float*)d_in[0];
    const float* yp = (const float*)d_in[1];
    const int*   z0 = (const int*)d_in[2];
    const int*   z1 = (const int*)d_in[3];
    const float* se = (const float*)d_in[4];
    const float* sb = (const float*)d_in[5];
    float* ws  = (float*)d_ws;
    float* out = (float*)d_out;

    hipMemsetAsync(d_ws, 0, (size_t)ZERO_FLOATS * sizeof(float), stream);
    hipLaunchKernelGGL(k_scatter, dim3(N_PTS / 256), dim3(256), 0, stream, yt, yp, z0, z1, ws);
    hipLaunchKernelGGL(k_build_s, dim3(32, 32), dim3(16, 16), 0, stream, se, sb, ws);
    for (int s = 0; s < 8; ++s) {
        int x = s * 64;
        hipLaunchKernelGGL(k_panel, dim3(1), dim3(512), 0, stream, ws, x);
        int T = 7 - s;
        if (T > 0) hipLaunchKernelGGL(k_update, dim3(T, T), dim3(256), 0, stream, ws, x);
    }
    hipLaunchKernelGGL(k_final, dim3(1), dim3(512), 0, stream, se, sb, ws, out);
}

// Round 4
// 498.641 us; speedup vs baseline: 1.4891x; 1.4891x over previous
//
#include <hip/hip_runtime.h>
#include <math.h>

// NLL of a Gaussian mixed model via double Schur complement / Woodbury.
// N=4096, two random-effect factors Q0=1000, Q1=500.
// Reduces the N x N solve to a 500x500 (padded 512) Cholesky, with the
// RHS appended as row 500 so the triangular solve happens during the
// factorization (row 500 of L = z = L^{-1} v).

constexpr int N_PTS = 4096;
constexpr int Q0 = 1000;
constexpr int Q1 = 500;
constexpr int QP = 512;            // Schur dim padded to 512 (row 500 = rhs, rest identity)
constexpr float LOG_2PI = 1.8378770664093453f;
constexpr float KAPPA = 16384.f;   // augmented diag; must exceed v^T S^{-1} v (~<= r^T r ~ 8200)

// ---- workspace layout (float offsets) ----
constexpr int OFF_CNT = 0;              // cross counts CNT[Q0][Q1]
constexpr int OFF_C0  = 500000;         // counts factor 0 [Q0]
constexpr int OFF_C1  = 501000;         // counts factor 1 [Q1]
constexpr int OFF_U0  = 501504;         // sum of r per group, factor 0 [Q0]
constexpr int OFF_U1  = 502504;         // sum of r per group, factor 1 [Q1]
constexpr int OFF_SC  = 503008;         // scalars: [0]=r^T r, [1]=sum log a, [2]=u0^T A^-1 u0
constexpr int OFF_S   = 503040;         // Schur matrix S [QP][QP], row stride QP
constexpr int ZERO_FLOATS = 503040;     // everything before S needs zeroing

__device__ __forceinline__ float readlane_f(float v, int l) {
    return __int_as_float(__builtin_amdgcn_readlane(__float_as_int(v), l));
}

// ------------------------------------------------------------------
// 1) scatter: counts, cross counts, group sums of residual, r^T r
// ------------------------------------------------------------------
__global__ __launch_bounds__(256) void k_scatter(const float* __restrict__ yt,
                                                 const float* __restrict__ yp,
                                                 const int* __restrict__ z0,
                                                 const int* __restrict__ z1,
                                                 float* __restrict__ ws) {
    int i = blockIdx.x * blockDim.x + threadIdx.x;
    float r = 0.f;
    if (i < N_PTS) {
        r = yt[i] - yp[i];
        int i0 = z0[i];
        int i1 = z1[i];
        atomicAdd(&ws[OFF_C0 + i0], 1.0f);
        atomicAdd(&ws[OFF_C1 + i1], 1.0f);
        atomicAdd(&ws[OFF_CNT + i0 * Q1 + i1], 1.0f);
        atomicAdd(&ws[OFF_U0 + i0], r);
        atomicAdd(&ws[OFF_U1 + i1], r);
    }
    float r2 = r * r;
    #pragma unroll
    for (int off = 32; off; off >>= 1) r2 += __shfl_down(r2, off, 64);
    if ((threadIdx.x & 63) == 0) atomicAdd(&ws[OFF_SC + 0], r2);
}

// ------------------------------------------------------------------
// 2) build S = D1 - B^T A^{-1} B  (padded to QP), row 500 = [U1 | kappa]
// ------------------------------------------------------------------
__global__ __launch_bounds__(256) void k_build_s(const float* __restrict__ sig2e,
                                                 const float* __restrict__ sig2bs,
                                                 float* __restrict__ ws) {
    const float se = sig2e[0], sb0 = sig2bs[0], sb1 = sig2bs[1];
    const float inv_se = 1.f / se, inv_sb0 = 1.f / sb0, inv_sb1 = 1.f / sb1;
    const float* CNT = ws + OFF_CNT;
    const float* C0w = ws + OFF_C0;
    const float* C1w = ws + OFF_C1;
    const float* U1w = ws + OFF_U1;
    float* S = ws + OFF_S;

    __shared__ float tI[32][17];
    __shared__ float tJ[32][17];
    __shared__ float wv[32];

    int tx = threadIdx.x, ty = threadIdx.y;
    int t = ty * 16 + tx;
    int i = blockIdx.y * 16 + ty;     // row of S
    int j = blockIdx.x * 16 + tx;     // col of S

    float acc = 0.f;
    for (int g0c = 0; g0c < Q0; g0c += 32) {
        #pragma unroll
        for (int l = 0; l < 2; ++l) {
            int e = t + l * 256;
            int kk = e >> 4, col = e & 15;
            int g0 = g0c + kk;
            int gi = blockIdx.y * 16 + col;
            int gj = blockIdx.x * 16 + col;
            tI[kk][col] = (g0 < Q0 && gi < Q1) ? CNT[g0 * Q1 + gi] : 0.f;
            tJ[kk][col] = (g0 < Q0 && gj < Q1) ? CNT[g0 * Q1 + gj] : 0.f;
        }
        if (t < 32) {
            int g0 = g0c + t;
            wv[t] = (g0 < Q0) ? 1.f / (inv_sb0 + C0w[g0] * inv_se) : 0.f;
        }
        __syncthreads();
        #pragma unroll
        for (int kk = 0; kk < 32; ++kk) acc += wv[kk] * (tI[kk][ty] * tJ[kk][tx]);
        __syncthreads();
    }

    float val;
    if (i < Q1 && j < Q1) {
        val = -inv_se * inv_se * acc;
        if (i == j) val += inv_sb1 + C1w[i] * inv_se;
    } else if (i == 500) {
        val = (j < Q1) ? U1w[j] : ((j == 500) ? KAPPA : 0.f);
    } else {
        val = (i == j) ? 1.f : 0.f;   // identity padding
    }
    S[i * QP + j] = val;
}

// ------------------------------------------------------------------
// 2b) rhs: S[500][c] -= inv_se * sum_g0 CNT[g0][c] * wu0[g0]  (atomics),
//     plus scalars: sum log a, u0^T A^{-1} u0.
//     One block per 32-row chunk of g0.
// ------------------------------------------------------------------
__global__ __launch_bounds__(256) void k_rhs(const float* __restrict__ sig2e,
                                             const float* __restrict__ sig2bs,
                                             float* __restrict__ ws) {
    const float se = sig2e[0], sb0 = sig2bs[0];
    const float inv_se = 1.f / se, inv_sb0 = 1.f / sb0;
    const float* CNT = ws + OFF_CNT;
    const float* C0w = ws + OFF_C0;
    const float* U0 = ws + OFF_U0;
    float* Srow = ws + OFF_S + 500 * QP;

    __shared__ float wu[32];
    int tid = threadIdx.x;
    int g0b = blockIdx.x * 32;
    int ng = Q0 - g0b; if (ng > 32) ng = 32;

    if (tid < 32) {
        float la = 0.f, q0 = 0.f, wuv = 0.f;
        if (tid < ng) {
            int g = g0b + tid;
            float a = inv_sb0 + C0w[g] * inv_se;
            wuv = U0[g] / a;
            la = logf(a);
            q0 = U0[g] * wuv;
        }
        wu[tid] = wuv;
        #pragma unroll
        for (int off = 16; off; off >>= 1) {
            la += __shfl_down(la, off, 32);
            q0 += __shfl_down(q0, off, 32);
        }
        if (tid == 0) {
            atomicAdd(&ws[OFF_SC + 1], la);
            atomicAdd(&ws[OFF_SC + 2], q0);
        }
    }
    __syncthreads();

    for (int c = tid; c < Q1; c += 256) {
        float acc = 0.f;
        #pragma unroll 8
        for (int g = 0; g < ng; ++g) acc += CNT[(g0b + g) * Q1 + c] * wu[g];
        atomicAdd(&Srow[c], -inv_se * acc);
    }
}

// ------------------------------------------------------------------
// 3a) panel kernel (single WG): register Cholesky of the 64x64 diagonal
//     block by wave 0 (lane = row, column broadcast via v_readlane),
//     then triangular solve of the rows below, thread-per-row, with a
//     per-wave register copy of the factored block (readlane broadcast,
//     zero LDS traffic).
// ------------------------------------------------------------------
__global__ __launch_bounds__(512) void k_panel(float* __restrict__ ws, int x) {
    float* S = ws + OFF_S;
    const int tid = threadIdx.x;
    const int lane = tid & 63;

    if (tid < 64) {
        // ---- factor 64x64 diagonal block, lane = row ----
        float d[64];
        const float* row = S + (size_t)(x + lane) * QP + x;
        #pragma unroll
        for (int c = 0; c < 16; ++c) {
            float4 v = *reinterpret_cast<const float4*>(row + 4 * c);
            d[4 * c + 0] = v.x; d[4 * c + 1] = v.y;
            d[4 * c + 2] = v.z; d[4 * c + 3] = v.w;
        }
        #pragma unroll
        for (int j = 0; j < 64; ++j) {
            float diag = readlane_f(d[j], j);
            float rs = rsqrtf(diag);
            d[j] *= rs;                  // lane j: diag*rs = sqrt(diag); lanes r>j: L[r][j]
            float lj = d[j];
            #pragma unroll
            for (int k = j + 1; k < 64; ++k) {
                float lkj = readlane_f(lj, k);   // L[k][j]
                d[k] = fmaf(-lj, lkj, d[k]);
            }
        }
        float* wrow = S + (size_t)(x + lane) * QP + x;
        #pragma unroll
        for (int c = 0; c < 16; ++c) {
            float4 v;
            v.x = (4 * c + 0 <= lane) ? d[4 * c + 0] : 0.f;
            v.y = (4 * c + 1 <= lane) ? d[4 * c + 1] : 0.f;
            v.z = (4 * c + 2 <= lane) ? d[4 * c + 2] : 0.f;
            v.w = (4 * c + 3 <= lane) ? d[4 * c + 3] : 0.f;
            *reinterpret_cast<float4*>(wrow + 4 * c) = v;
        }
    }
    __syncthreads();

    // ---- panel triangular solve: thread = row, wave-private D copy ----
    int r = x + 64 + (tid - 64);
    if (tid >= 64 && r < QP) {
        float dreg[64];
        const float* drow = S + (size_t)(x + lane) * QP + x;  // lane = local row of D
        #pragma unroll
        for (int c = 0; c < 16; ++c) {
            float4 v = *reinterpret_cast<const float4*>(drow + 4 * c);
            dreg[4 * c + 0] = v.x; dreg[4 * c + 1] = v.y;
            dreg[4 * c + 2] = v.z; dreg[4 * c + 3] = v.w;
        }
        float p[64];
        float* prow = S + (size_t)r * QP + x;
        #pragma unroll
        for (int c = 0; c < 16; ++c) {
            float4 v = *reinterpret_cast<const float4*>(prow + 4 * c);
            p[4 * c + 0] = v.x; p[4 * c + 1] = v.y;
            p[4 * c + 2] = v.z; p[4 * c + 3] = v.w;
        }
        #pragma unroll
        for (int j = 0; j < 64; ++j) {
            float diag = readlane_f(dreg[j], j);
            float pj = p[j] / diag;
            p[j] = pj;
            #pragma unroll
            for (int k = j + 1; k < 64; ++k) {
                float lkj = readlane_f(dreg[j], k);  // L[k][j]
                p[k] = fmaf(-pj, lkj, p[k]);
            }
        }
        #pragma unroll
        for (int c = 0; c < 16; ++c) {
            float4 v;
            v.x = p[4 * c + 0]; v.y = p[4 * c + 1];
            v.z = p[4 * c + 2]; v.w = p[4 * c + 3];
            *reinterpret_cast<float4*>(prow + 4 * c) = v;
        }
    }
}

// ------------------------------------------------------------------
// 3b) trailing SYRK update: S[i][k] -= sum_j P[i][j]*P[k][j] (lower only)
// ------------------------------------------------------------------
__global__ __launch_bounds__(256) void k_update(float* __restrict__ ws, int x) {
    float* S = ws + OFF_S;
    int ti = blockIdx.y, tj = blockIdx.x;
    if (tj > ti) return;
    int ri = x + 64 + ti * 64;
    int rj = x + 64 + tj * 64;

    __shared__ float Pi[64][65];
    __shared__ float Pj[64][65];
    int tid = threadIdx.x;

    #pragma unroll
    for (int it = 0; it < 16; ++it) {
        int e = tid + it * 256;
        int a = e >> 6, b = e & 63;
        Pi[a][b] = S[(ri + a) * QP + x + b];
        Pj[a][b] = S[(rj + a) * QP + x + b];
    }
    __syncthreads();

    int ta = tid >> 4, tb = tid & 15;   // 16x16 threads, 4x4 micro-tile
    float acc[4][4] = {{0.f}};
    #pragma unroll
    for (int j = 0; j < 64; ++j) {
        float pa[4], pb[4];
        #pragma unroll
        for (int u = 0; u < 4; ++u) { pa[u] = Pi[ta * 4 + u][j]; pb[u] = Pj[tb * 4 + u][j]; }
        #pragma unroll
        for (int u = 0; u < 4; ++u)
            #pragma unroll
            for (int v = 0; v < 4; ++v) acc[u][v] += pa[u] * pb[v];
    }

    if (ti > tj) {
        #pragma unroll
        for (int u = 0; u < 4; ++u) {
            float4* ptr = (float4*)&S[(ri + ta * 4 + u) * QP + rj + tb * 4];
            float4 cv = *ptr;
            cv.x -= acc[u][0]; cv.y -= acc[u][1]; cv.z -= acc[u][2]; cv.w -= acc[u][3];
            *ptr = cv;
        }
    } else {
        #pragma unroll
        for (int u = 0; u < 4; ++u)
            #pragma unroll
            for (int v = 0; v < 4; ++v) {
                int gi = ri + ta * 4 + u, gj = rj + tb * 4 + v;
                if (gi >= gj) S[gi * QP + gj] -= acc[u][v];
            }
    }
}

// ------------------------------------------------------------------
// 4) final: z^T z from factored row 500, logdet from the diagonal,
//    combine with scalar partials.
// ------------------------------------------------------------------
__device__ __forceinline__ float block_reduce512(float v, float* red, int tid) {
    __syncthreads();
    red[tid] = v;
    __syncthreads();
    if (tid < 256) red[tid] += red[tid + 256];
    __syncthreads();
    if (tid < 128) red[tid] += red[tid + 128];
    __syncthreads();
    if (tid < 64) red[tid] += red[tid + 64];
    __syncthreads();
    float x = 0.f;
    if (tid < 64) {
        x = red[tid];
        #pragma unroll
        for (int o = 32; o; o >>= 1) x += __shfl_down(x, o, 64);
    }
    return x;   // valid on tid 0
}

__global__ __launch_bounds__(512) void k_final(const float* __restrict__ sig2e,
                                               const float* __restrict__ sig2bs,
                                               float* __restrict__ ws,
                                               float* __restrict__ out) {
    const float se = sig2e[0], sb0 = sig2bs[0], sb1 = sig2bs[1];
    const float inv_se = 1.f / se;
    float* S = ws + OFF_S;
    __shared__ float red[512];
    int tid = threadIdx.x;

    float zz = 0.f, ld = 0.f;
    if (tid < Q1) {
        float z = S[500 * QP + tid];     // row 500 of L = z = L^{-1} v
        zz = z * z;
        ld = logf(S[tid * QP + tid]);    // log L[i][i], i < 500
    }
    float zz_sum = block_reduce512(zz, red, tid);
    float ld_sum = block_reduce512(ld, red, tid);

    if (tid == 0) {
        float rtr = ws[OFF_SC + 0];
        float la  = ws[OFF_SC + 1];
        float q0p = ws[OFF_SC + 2];
        float umu = q0p + zz_sum;                            // u^T M^{-1} u
        float loss2 = inv_se * rtr - inv_se * inv_se * umu;  // r^T V^{-1} r
        float logdetV = (float)N_PTS * logf(se)
                      + (float)Q0 * logf(sb0)
                      + (float)Q1 * logf(sb1)
                      + la                                   // sum log a[g0]
                      + 2.f * ld_sum;                        // logdet S
        out[0] = 0.5f * ((float)N_PTS * LOG_2PI + logdetV + loss2);
    }
}

// ------------------------------------------------------------------
extern "C" void kernel_launch(void* const* d_in, const int* in_sizes, int n_in,
                              void* d_out, int out_size, void* d_ws, size_t ws_size,
                              hipStream_t stream) {
    const float* yt = (const float*)d_in[0];
    const float* yp = (const float*)d_in[1];
    const int*   z0 = (const int*)d_in[2];
    const int*   z1 = (const int*)d_in[3];
    const float* se = (const float*)d_in[4];
    const float* sb = (const float*)d_in[5];
    float* ws  = (float*)d_ws;
    float* out = (float*)d_out;

    hipMemsetAsync(d_ws, 0, (size_t)ZERO_FLOATS * sizeof(float), stream);
    hipLaunchKernelGGL(k_scatter, dim3(N_PTS / 256), dim3(256), 0, stream, yt, yp, z0, z1, ws);
    hipLaunchKernelGGL(k_build_s, dim3(32, 32), dim3(16, 16), 0, stream, se, sb, ws);
    hipLaunchKernelGGL(k_rhs, dim3(32), dim3(256), 0, stream, se, sb, ws);
    for (int s = 0; s < 8; ++s) {
        int x = s * 64;
        hipLaunchKernelGGL(k_panel, dim3(1), dim3(512), 0, stream, ws, x);
        int T = 7 - s;
        if (T > 0) hipLaunchKernelGGL(k_update, dim3(T, T), dim3(256), 0, stream, ws, x);
    }
    hipLaunchKernelGGL(k_final, dim3(1), dim3(512), 0, stream, se, sb, ws, out);
}

// Round 5
// 396.252 us; speedup vs baseline: 1.8739x; 1.2584x over previous
//
#include <hip/hip_runtime.h>
#include <math.h>

// NLL of a Gaussian mixed model via double Schur complement / Woodbury.
// N=4096, factors Q0=1000, Q1=500. The N x N solve reduces to a 500x500
// (padded 512) Cholesky with the RHS appended as row 500 (augmented-row
// trick: z^T z = KAPPA - L[500][500]^2, logdet from diag of L).
// Build is SPARSE: CNT has only 4096 nonzeros, so S is assembled by
// pair-enumeration over points grouped by z0 (~21k atomics) instead of a
// dense 500x1000x500 SYRK. The whole Cholesky runs in ONE persistent
// 28-block kernel with manual device-scope grid barriers (8 total).

constexpr int N_PTS = 4096;
constexpr int Q0 = 1000;
constexpr int Q1 = 500;
constexpr int QP = 512;
constexpr float LOG_2PI = 1.8378770664093453f;
constexpr float KAPPA = 16384.f;   // > z^T z (~<= r^T r ~ 8200)

// ---- workspace layout (float offsets) ----
constexpr int OFF_C0   = 0;        // counts factor 0 [1000]
constexpr int OFF_C1   = 1024;     // counts factor 1 [500]
constexpr int OFF_U0   = 2048;     // residual sums factor 0 [1000]
constexpr int OFF_U1   = 3072;     // residual sums factor 1 [500]
constexpr int OFF_SC   = 3584;     // [0]=r^T r  [1]=sum log a  [2]=u0^T A^-1 u0
constexpr int OFF_BAR  = 3596;     // grid-barrier counter (uint)
constexpr int ZERO_FLOATS = 3600;  // memset range (everything above is fully overwritten)
constexpr int OFF_OFFS = 3600;     // int[1024] exclusive offsets of sorted groups
constexpr int OFF_CURS = 4624;     // int[1024] scatter cursors
constexpr int OFF_SRT  = 5648;     // int[4096] z1 of points sorted by z0
constexpr int OFF_S    = 10240;    // S [QP][QP]
constexpr int NB_CHOL  = 28;       // persistent Cholesky blocks (= tiles at step 0)

__device__ __forceinline__ float readlane_f(float v, int l) {
    return __int_as_float(__builtin_amdgcn_readlane(__float_as_int(v), l));
}

// ------------------------------------------------------------------
// 1) scatter: per-group counts, residual sums, r^T r
// ------------------------------------------------------------------
__global__ __launch_bounds__(256) void k_scatter(const float* __restrict__ yt,
                                                 const float* __restrict__ yp,
                                                 const int* __restrict__ z0,
                                                 const int* __restrict__ z1,
                                                 float* __restrict__ ws) {
    int i = blockIdx.x * blockDim.x + threadIdx.x;
    float r = 0.f;
    if (i < N_PTS) {
        r = yt[i] - yp[i];
        int i0 = z0[i];
        int i1 = z1[i];
        atomicAdd(&ws[OFF_C0 + i0], 1.0f);
        atomicAdd(&ws[OFF_C1 + i1], 1.0f);
        atomicAdd(&ws[OFF_U0 + i0], r);
        atomicAdd(&ws[OFF_U1 + i1], r);
    }
    float r2 = r * r;
    #pragma unroll
    for (int off = 32; off; off >>= 1) r2 += __shfl_down(r2, off, 64);
    if ((threadIdx.x & 63) == 0) atomicAdd(&ws[OFF_SC + 0], r2);
}

// ------------------------------------------------------------------
// 2) prefix: exclusive scan of group-0 counts -> offsets + cursors
// ------------------------------------------------------------------
__global__ __launch_bounds__(1024) void k_prefix(float* __restrict__ ws) {
    __shared__ int lds[1024];
    int tid = threadIdx.x;
    int v = (tid < Q0) ? (int)ws[OFF_C0 + tid] : 0;
    lds[tid] = v;
    __syncthreads();
    for (int off = 1; off < 1024; off <<= 1) {
        int add = (tid >= off) ? lds[tid - off] : 0;
        __syncthreads();
        lds[tid] += add;
        __syncthreads();
    }
    int excl = lds[tid] - v;
    ((int*)(ws + OFF_OFFS))[tid] = excl;
    ((int*)(ws + OFF_CURS))[tid] = excl;
}

// ------------------------------------------------------------------
// 3) counting-sort scatter: z1 values of points, grouped by z0
// ------------------------------------------------------------------
__global__ __launch_bounds__(256) void k_sortscatter(const int* __restrict__ z0,
                                                     const int* __restrict__ z1,
                                                     float* __restrict__ ws) {
    int i = blockIdx.x * blockDim.x + threadIdx.x;
    if (i < N_PTS) {
        int g = z0[i];
        int slot = atomicAdd(&((int*)(ws + OFF_CURS))[g], 1);
        ((int*)(ws + OFF_SRT))[slot] = z1[i];
    }
}

// ------------------------------------------------------------------
// 4) init S base: zeros, diag = 1/sb1 + C1/se, row 500 = [U1 | KAPPA],
//    identity padding rows 501..511
// ------------------------------------------------------------------
__global__ __launch_bounds__(256) void k_init_s(const float* __restrict__ sig2e,
                                                const float* __restrict__ sig2bs,
                                                float* __restrict__ ws) {
    const float inv_se = 1.f / sig2e[0], inv_sb1 = 1.f / sig2bs[1];
    const float* C1w = ws + OFF_C1;
    const float* U1w = ws + OFF_U1;
    int idx = blockIdx.x * 256 + threadIdx.x;   // one float4 per thread
    int i = idx >> 7;                            // row
    int j0 = (idx & 127) << 2;                   // col base
    float4 v;
    float* e = &v.x;
    #pragma unroll
    for (int t = 0; t < 4; ++t) {
        int j = j0 + t;
        float x = 0.f;
        if (i == 500)      x = (j < Q1) ? U1w[j] : ((j == 500) ? KAPPA : 0.f);
        else if (i == j)   x = (i < Q1) ? (inv_sb1 + C1w[i] * inv_se) : 1.f;
        e[t] = x;
    }
    *reinterpret_cast<float4*>(ws + OFF_S + (size_t)i * QP + j0) = v;
}

// ------------------------------------------------------------------
// 5) sparse pair assembly: thread per group g0.
//    S[i][j]   += -1/se^2 * w_g   for each ordered point-pair (i>=j)
//    S[500][c] += -1/se * w_g*U0_g per point (RHS fold-in)
//    scalars: sum log a, u0^T A^-1 u0
// ------------------------------------------------------------------
__global__ __launch_bounds__(256) void k_pairs(const float* __restrict__ sig2e,
                                               const float* __restrict__ sig2bs,
                                               float* __restrict__ ws) {
    const float inv_se = 1.f / sig2e[0], inv_sb0 = 1.f / sig2bs[0];
    int g = blockIdx.x * 256 + threadIdx.x;
    if (g >= Q0) return;
    const int* offs = (const int*)(ws + OFF_OFFS);
    const int* srt  = (const int*)(ws + OFF_SRT);
    float* S = ws + OFF_S;

    float cg = ws[OFF_C0 + g];
    float a  = inv_sb0 + cg * inv_se;
    float u0 = ws[OFF_U0 + g];
    float wu = u0 / a;
    atomicAdd(&ws[OFF_SC + 1], logf(a));
    atomicAdd(&ws[OFF_SC + 2], u0 * wu);

    int beg = offs[g];
    int cnt = (int)cg;
    float coef = -inv_se * inv_se / a;      // -1/se^2 * w_g
    float rhsv = -inv_se * wu;
    for (int ia = beg; ia < beg + cnt; ++ia) {
        int ca = srt[ia];
        atomicAdd(&S[(size_t)500 * QP + ca], rhsv);
        for (int ib = beg; ib < beg + cnt; ++ib) {
            int cb = srt[ib];
            if (ca >= cb) atomicAdd(&S[(size_t)ca * QP + cb], coef);
        }
    }
}

// ------------------------------------------------------------------
// 6) persistent Cholesky: 28 blocks, manual grid barriers.
// ------------------------------------------------------------------
__device__ __forceinline__ void gbar(unsigned* cnt, int* it) {
    __syncthreads();
    if (threadIdx.x == 0) {
        __threadfence();                       // release
        atomicAdd(cnt, 1u);
        unsigned target = (unsigned)NB_CHOL * (unsigned)(++(*it));
        while (atomicAdd(cnt, 0u) < target) __builtin_amdgcn_s_sleep(2);
        __threadfence();                       // acquire
    }
    __syncthreads();
}

// register Cholesky of a 64x64 block (lane = row), then masked store
__device__ __forceinline__ void chol64_store(float (&d)[64], float* S, int base, int lane) {
    #pragma unroll
    for (int j = 0; j < 64; ++j) {
        float diag = readlane_f(d[j], j);
        float rs = rsqrtf(diag);
        d[j] *= rs;
        float lj = d[j];
        #pragma unroll
        for (int k = j + 1; k < 64; ++k)
            d[k] = fmaf(-lj, readlane_f(lj, k), d[k]);
    }
    float* wr = S + (size_t)(base + lane) * QP + base;
    #pragma unroll
    for (int c = 0; c < 16; ++c) {
        float4 v;
        v.x = (4 * c + 0 <= lane) ? d[4 * c + 0] : 0.f;
        v.y = (4 * c + 1 <= lane) ? d[4 * c + 1] : 0.f;
        v.z = (4 * c + 2 <= lane) ? d[4 * c + 2] : 0.f;
        v.w = (4 * c + 3 <= lane) ? d[4 * c + 3] : 0.f;
        *reinterpret_cast<float4*>(wr + 4 * c) = v;
    }
}

// triangular solve of 64 panel rows (lane = row) against factored D at x;
// result written to LDS tile
__device__ __forceinline__ void solve_tile(const float* S, int x, int g0,
                                           float (*out)[65], int lane) {
    float dreg[64], p[64];
    const float* dr = S + (size_t)(x + lane) * QP + x;
    const float* pr = S + (size_t)(g0 + lane) * QP + x;
    #pragma unroll
    for (int c = 0; c < 16; ++c) {
        float4 v = *reinterpret_cast<const float4*>(dr + 4 * c);
        dreg[4 * c] = v.x; dreg[4 * c + 1] = v.y; dreg[4 * c + 2] = v.z; dreg[4 * c + 3] = v.w;
        float4 q = *reinterpret_cast<const float4*>(pr + 4 * c);
        p[4 * c] = q.x; p[4 * c + 1] = q.y; p[4 * c + 2] = q.z; p[4 * c + 3] = q.w;
    }
    #pragma unroll
    for (int j = 0; j < 64; ++j) {
        float diag = readlane_f(dreg[j], j);
        float pj = p[j] / diag;
        p[j] = pj;
        #pragma unroll
        for (int k = j + 1; k < 64; ++k)
            p[k] = fmaf(-pj, readlane_f(dreg[j], k), p[k]);
    }
    #pragma unroll
    for (int k = 0; k < 64; ++k) out[lane][k] = p[k];
}

__global__ __launch_bounds__(256) void k_chol(const float* __restrict__ sig2e,
                                              const float* __restrict__ sig2bs,
                                              float* __restrict__ ws,
                                              float* __restrict__ out) {
    float* S = ws + OFF_S;
    unsigned* bar = (unsigned*)(ws + OFF_BAR);
    const int tid = threadIdx.x;
    const int lane = tid & 63;
    const int w = tid >> 6;
    const int blk = blockIdx.x;
    __shared__ float Pi[64][65];
    __shared__ float Pj[64][65];
    int bit = 0;

    // prologue: block 0 factors D0
    if (blk == 0 && w == 0) {
        float d[64];
        const float* row = S + (size_t)lane * QP;
        #pragma unroll
        for (int c = 0; c < 16; ++c) {
            float4 v = *reinterpret_cast<const float4*>(row + 4 * c);
            d[4 * c] = v.x; d[4 * c + 1] = v.y; d[4 * c + 2] = v.z; d[4 * c + 3] = v.w;
        }
        chol64_store(d, S, 0, lane);
    }
    gbar(bar, &bit);

    for (int s = 0; s < 7; ++s) {
        const int x = 64 * s;
        const int T = 7 - s;
        const int nt = T * (T + 1) / 2;
        if (blk < nt) {
            int ti = 0;
            while ((ti + 1) * (ti + 2) / 2 <= blk) ++ti;
            int tj = blk - ti * (ti + 1) / 2;
            const int gi0 = x + 64 + 64 * ti;
            const int gj0 = x + 64 + 64 * tj;

            // redundant panel solves, straight into LDS
            if (w == 0)                     solve_tile(S, x, gi0, Pi, lane);
            else if (w == 1 && ti != tj)    solve_tile(S, x, gj0, Pj, lane);
            __syncthreads();

            // SYRK update of the trailing tile
            float (*PJ)[65] = (ti == tj) ? Pi : Pj;
            const int ta = tid >> 4, tb = tid & 15;
            float acc[4][4] = {{0.f}};
            #pragma unroll
            for (int j = 0; j < 64; ++j) {
                float pa[4], pb[4];
                #pragma unroll
                for (int u = 0; u < 4; ++u) { pa[u] = Pi[ta * 4 + u][j]; pb[u] = PJ[tb * 4 + u][j]; }
                #pragma unroll
                for (int u = 0; u < 4; ++u)
                    #pragma unroll
                    for (int v = 0; v < 4; ++v) acc[u][v] += pa[u] * pb[v];
            }

            if (ti > tj) {
                #pragma unroll
                for (int u = 0; u < 4; ++u) {
                    float4* ptr = (float4*)&S[(size_t)(gi0 + ta * 4 + u) * QP + gj0 + tb * 4];
                    float4 cv = *ptr;
                    cv.x -= acc[u][0]; cv.y -= acc[u][1]; cv.z -= acc[u][2]; cv.w -= acc[u][3];
                    *ptr = cv;
                }
            } else {
                float nv[4][4];
                #pragma unroll
                for (int u = 0; u < 4; ++u) {
                    float4 cv = *(const float4*)&S[(size_t)(gi0 + ta * 4 + u) * QP + gj0 + tb * 4];
                    nv[u][0] = cv.x - acc[u][0]; nv[u][1] = cv.y - acc[u][1];
                    nv[u][2] = cv.z - acc[u][2]; nv[u][3] = cv.w - acc[u][3];
                }
                #pragma unroll
                for (int u = 0; u < 4; ++u)
                    #pragma unroll
                    for (int v = 0; v < 4; ++v) {
                        int gi = gi0 + ta * 4 + u, gj = gj0 + tb * 4 + v;
                        if (gi >= gj) S[(size_t)gi * QP + gj] = nv[u][v];
                    }
                if (ti == 0) {   // stage full updated tile for in-step factor
                    #pragma unroll
                    for (int u = 0; u < 4; ++u)
                        #pragma unroll
                        for (int v = 0; v < 4; ++v)
                            Pj[ta * 4 + u][tb * 4 + v] = nv[u][v];
                }
            }

            // block 0 == tile (0,0): factor the next diagonal block in-step
            if (blk == 0) {
                __syncthreads();
                if (w == 0) {
                    float d[64];
                    #pragma unroll
                    for (int k = 0; k < 64; ++k) d[k] = Pj[lane][k];
                    chol64_store(d, S, x + 64, lane);
                }
            }
        }
        gbar(bar, &bit);
    }

    // epilogue: block 0 reduces logdet + combines scalars
    if (blk == 0) {
        const float se = sig2e[0], sb0 = sig2bs[0], sb1 = sig2bs[1];
        const float inv_se = 1.f / se;
        float ld = 0.f;
        for (int i = tid; i < Q1; i += 256) ld += logf(S[(size_t)i * QP + i]);
        float* red = &Pi[0][0];
        __syncthreads();
        red[tid] = ld;
        __syncthreads();
        if (tid < 128) red[tid] += red[tid + 128];
        __syncthreads();
        if (tid < 64) red[tid] += red[tid + 64];
        __syncthreads();
        if (tid < 64) {
            float v = red[tid];
            #pragma unroll
            for (int o = 32; o; o >>= 1) v += __shfl_down(v, o, 64);
            if (tid == 0) {
                float L55 = S[(size_t)500 * QP + 500];
                float zz = KAPPA - L55 * L55;          // z^T z = v^T S^-1 v
                float rtr = ws[OFF_SC + 0];
                float la  = ws[OFF_SC + 1];
                float q0p = ws[OFF_SC + 2];
                float umu = q0p + zz;                  // u^T M^-1 u
                float loss2 = inv_se * rtr - inv_se * inv_se * umu;
                float logdetV = (float)N_PTS * logf(se)
                              + (float)Q0 * logf(sb0)
                              + (float)Q1 * logf(sb1)
                              + la + 2.f * v;
                out[0] = 0.5f * ((float)N_PTS * LOG_2PI + logdetV + loss2);
            }
        }
    }
}

// ------------------------------------------------------------------
extern "C" void kernel_launch(void* const* d_in, const int* in_sizes, int n_in,
                              void* d_out, int out_size, void* d_ws, size_t ws_size,
                              hipStream_t stream) {
    const float* yt = (const float*)d_in[0];
    const float* yp = (const float*)d_in[1];
    const int*   z0 = (const int*)d_in[2];
    const int*   z1 = (const int*)d_in[3];
    const float* se = (const float*)d_in[4];
    const float* sb = (const float*)d_in[5];
    float* ws  = (float*)d_ws;
    float* out = (float*)d_out;

    hipMemsetAsync(d_ws, 0, (size_t)ZERO_FLOATS * sizeof(float), stream);
    hipLaunchKernelGGL(k_scatter, dim3(N_PTS / 256), dim3(256), 0, stream, yt, yp, z0, z1, ws);
    hipLaunchKernelGGL(k_prefix, dim3(1), dim3(1024), 0, stream, ws);
    hipLaunchKernelGGL(k_sortscatter, dim3(N_PTS / 256), dim3(256), 0, stream, z0, z1, ws);
    hipLaunchKernelGGL(k_init_s, dim3(QP * QP / 4 / 256), dim3(256), 0, stream, se, sb, ws);
    hipLaunchKernelGGL(k_pairs, dim3(4), dim3(256), 0, stream, se, sb, ws);
    hipLaunchKernelGGL(k_chol, dim3(NB_CHOL), dim3(256), 0, stream, se, sb, ws, out);
}